// Round 6
// baseline (121.819 us; speedup 1.0000x reference)
//
#include <hip/hip_runtime.h>

#define BATCH  65536
#define NIN    9
#define NHID   100
#define TSTEPS 25
#define CHUNK  5
#define EPS    3e-5f

typedef float v2f __attribute__((ext_vector_type(2)));

// ROUND-22: break cross-j serialization. R18/R20/R21 showed instruction-mix
// edits don't move the 41us / VALUBusy-70% plateau. Theory: the per-j
// fallback branch (__any + patch block) is a scheduling wall — the compiler
// can't hoist j+1's s_loads or interleave j+1's independent u-chain across
// it (which is why unroll pragmas were no-ops). Fix: explicit 2-way fusion.
// Each iteration runs TWO bit-exact R17 chains (h and h+1) in one
// straight-line t-loop; both fallbacks run AFTER the fused loop. s_load
// latency amortized 2x, chain latency fully hidden by the sibling chain.
// Numerics: chain formulation unchanged; per-address accumulate order stays
// j-then-j+1 (A fmacs before B at each t). Only rare patch ordering moves
// (ulp-level, arbiter decisions unchanged). Tail j=24 = original body.
__global__ __launch_bounds__(256, 4) void snn_kernel(
    const float* __restrict__ x,  const float* __restrict__ W1,
    const float* __restrict__ b1, const float* __restrict__ W2,
    const float* __restrict__ b2, float* __restrict__ out)
{
    __shared__ float sx[64 * NIN];              // 2.25 KB staged x rows
    __shared__ v2f   sacc[2][4][CHUNK][64];     // 20.5 KB double-buffered reduce

    const int tid  = threadIdx.x;
    const int lane = tid & 63;
    const int wq   = __builtin_amdgcn_readfirstlane(tid >> 6);
    const int b0   = blockIdx.x * 64;

    for (int i = tid; i < 64 * NIN; i += 256) sx[i] = x[(size_t)b0 * NIN + i];
    __syncthreads();

    // per-lane x row, f32 (exact input values)
    float xv[NIN];
#pragma unroll
    for (int i = 0; i < NIN; ++i) xv[i] = sx[lane * NIN + i];

    // per-step fc2 partial sums
    float a0[TSTEPS], a1[TSTEPS];
#pragma unroll
    for (int t = 0; t < TSTEPS; ++t) { a0[t] = 0.f; a1[t] = 0.f; }

    // rare wave-uniform exact fallback: f32 replay (same fmaf sequence as
    // the main chain) vs the EXACT f64 chain; patch where decisions differ.
    auto fallback = [&](int h, float k, float k1, float w0, float w1) {
        double c64 = 0.0;
#pragma unroll
        for (int i = 0; i < NIN; ++i)
            c64 += (double)W1[h * NIN + i] * (double)xv[i];
        c64 += (double)b1[h];
        const double c1 = c64 - 1.0;

        double md = 0.0;  bool sd = false;   // exact f64 chain
        float  ur = -1.0f; bool sr = false;  // f32 replay (matches main)
#pragma unroll
        for (int t = 0; t < TSTEPS; ++t) {
            ur = fmaf(0.95f, ur, sr ? k1 : k);
            sr = (ur > 0.0f);
            md = 0.95 * md + (sd ? c1 : c64);
            sd = (md > 1.0);
            if (sr != sd) {                  // patch to the f64 decision
                const float sg = sd ? 1.f : -1.f;
                a0[t] = fmaf(sg, w0, a0[t]);
                a1[t] = fmaf(sg, w1, a1[t]);
            }
        }
    };

    const int h0 = wq * 25;
#pragma unroll 1
    for (int jj = 0; jj < 24; jj += 2) {
        const int hA = h0 + jj, hB = hA + 1;
        float cA = 0.f, cB = 0.f;
#pragma unroll
        for (int i = 0; i < NIN; ++i) {
            cA = fmaf(W1[hA * NIN + i], xv[i], cA);
            cB = fmaf(W1[hB * NIN + i], xv[i], cB);
        }
        cA += b1[hA]; cB += b1[hB];
        const float kA = cA - 0.05f, k1A = cA - 1.05f;
        const float kB = cB - 0.05f, k1B = cB - 1.05f;
        const float w0A = W2[hA], w1A = W2[NHID + hA];
        const float w0B = W2[hB], w1B = W2[NHID + hB];

        float uA = -1.f, uB = -1.f, mgA = 1e30f, mgB = 1e30f;
        bool  sA = false, sB = false;
#pragma unroll
        for (int t = 0; t < TSTEPS; ++t) {
            uA = fmaf(0.95f, uA, sA ? k1A : kA);   // chain A (bit-exact R17)
            uB = fmaf(0.95f, uB, sB ? k1B : kB);   // chain B, independent
            sA = (uA > 0.f);
            sB = (uB > 0.f);
            mgA = fminf(mgA, fabsf(uA));
            mgB = fminf(mgB, fabsf(uB));
            const float dA = sA ? 1.f : 0.f;
            const float dB = sB ? 1.f : 0.f;
            a0[t] = fmaf(dA, w0A, a0[t]);          // A before B: j-order
            a1[t] = fmaf(dA, w1A, a1[t]);
            a0[t] = fmaf(dB, w0B, a0[t]);
            a1[t] = fmaf(dB, w1B, a1[t]);
        }
        if (__any(mgA < EPS)) fallback(hA, kA, k1A, w0A, w1A);
        if (__any(mgB < EPS)) fallback(hB, kB, k1B, w0B, w1B);
    }
    {   // tail unit j=24 (original single-chain body)
        const int h = h0 + 24;
        float c32 = 0.f;
#pragma unroll
        for (int i = 0; i < NIN; ++i) c32 = fmaf(W1[h * NIN + i], xv[i], c32);
        c32 += b1[h];
        const float k  = c32 - 0.05f;
        const float k1 = c32 - 1.05f;
        const float w0 = W2[h], w1 = W2[NHID + h];

        float u = -1.0f, ming = 1e30f;
        bool  s = false;
#pragma unroll
        for (int t = 0; t < TSTEPS; ++t) {
            u = fmaf(0.95f, u, s ? k1 : k);
            s = (u > 0.0f);
            ming = fminf(ming, fabsf(u));
            const float d = s ? 1.f : 0.f;
            a0[t] = fmaf(d, w0, a0[t]);
            a1[t] = fmaf(d, w1, a1[t]);
        }
        if (__any(ming < EPS)) fallback(h, k, k1, w0, w1);
    }

    // chunked cross-wave reduce + mem2 (wave 0), double-buffered LDS.
    // All acc indices compile-time constants (round-9 lesson).
    double m20 = 0.0, m21 = 0.0;
    double bb0 = (double)b2[0], bb1 = (double)b2[1];

#pragma unroll
    for (int k = 0; k < TSTEPS / CHUNK; ++k) {
#pragma unroll
        for (int u = 0; u < CHUNK; ++u)
            sacc[k & 1][wq][u][lane] = (v2f){a0[k * CHUNK + u], a1[k * CHUNK + u]};
        __syncthreads();
        // wave0 reads buf[k&1] before the NEXT barrier; other waves can't
        // overwrite buf[k&1] until chunk k+2's writes, behind that barrier.
        if (wq == 0) {
#pragma unroll
            for (int u = 0; u < CHUNK; ++u) {
                const int t = k * CHUNK + u;
                v2f q0 = sacc[k & 1][0][u][lane];
                v2f q1 = sacc[k & 1][1][u][lane];
                v2f q2 = sacc[k & 1][2][u][lane];
                v2f q3 = sacc[k & 1][3][u][lane];
                v2f sum = (q0 + q1) + (q2 + q3);   // butterfly bracketing
                double r0 = (m20 > 1.0) ? 1.0 : 0.0;
                double r1 = (m21 > 1.0) ? 1.0 : 0.0;
                m20 = 0.95 * m20 + ((double)sum[0] + bb0) - r0;
                m21 = 0.95 * m21 + ((double)sum[1] + bb1) - r1;
                *(float2*)(out + ((size_t)t * BATCH + b0 + lane) * 2) =
                    make_float2((float)m20, (float)m21);
            }
        }
    }
}

extern "C" void kernel_launch(void* const* d_in, const int* in_sizes, int n_in,
                              void* d_out, int out_size, void* d_ws, size_t ws_size,
                              hipStream_t stream) {
    const float* x  = (const float*)d_in[0];
    const float* W1 = (const float*)d_in[1];
    const float* b1 = (const float*)d_in[2];
    const float* W2 = (const float*)d_in[3];
    const float* b2 = (const float*)d_in[4];
    float* out = (float*)d_out;

    dim3 grid(BATCH / 64), block(256);
    hipLaunchKernelGGL(snn_kernel, grid, block, 0, stream, x, W1, b1, W2, b2, out);
}

// Round 7
// 112.730 us; speedup vs baseline: 1.0806x; 1.0806x over previous
//
#include <hip/hip_runtime.h>

#define BATCH  65536
#define NIN    9
#define NHID   100
#define TSTEPS 25
#define CHUNK  5
#define EPS    3e-5f

typedef float v2f __attribute__((ext_vector_type(2)));

// ROUND-23: two-phase bit-train restructure. Evidence: R17-R20 = 41us
// plateau with arrays AGPR-offloaded (VGPR_Count 44 arch, tax ~2500
// instr/thread); R22 = 2-way fusion overflowed to SCRATCH (FETCH x10,
// WRITE +23MB, 65us). Fix: never keep 50 accumulators and chains live
// together. Phase 1: run each unit's chain, record the 25-step spike
// train as a 25-bit mask (2 ops/step), store to LDS sbits[wq][j][lane]
// (same-thread RAW, no barrier). Fallback moves OUT of the hot loop:
// wave-uniform badmask accumulates per-j triggers; rare f64-arbitrated
// bit-flips are XOR-patched into sbits afterward -> phase-1 j-loop is
// BRANCH-FREE (kills the R22 scheduling wall as well). Phase 2:
// t-chunked, j unrolled: only 10 live accumulators (bfe+cvt extracts d;
// W2 wave-uniform s_loads). Peak live state fits arch VGPRs everywhere;
// AGPR tax eliminated by construction. Per-address accumulate order
// stays j-ascending == R17; decisions still f64-arbitrated.
__global__ __launch_bounds__(256) void snn_kernel(
    const float* __restrict__ x,  const float* __restrict__ W1,
    const float* __restrict__ b1, const float* __restrict__ W2,
    const float* __restrict__ b2, float* __restrict__ out)
{
    __shared__ float sx[64 * NIN];              // 2.25 KB staged x rows
    __shared__ unsigned int sbits[4][25][64];   // 25.6 KB spike bit-trains
    __shared__ v2f   sacc[2][4][CHUNK][64];     // 20.5 KB double-buffered reduce

    const int tid  = threadIdx.x;
    const int lane = tid & 63;
    const int wq   = __builtin_amdgcn_readfirstlane(tid >> 6);
    const int b0   = blockIdx.x * 64;

    for (int i = tid; i < 64 * NIN; i += 256) sx[i] = x[(size_t)b0 * NIN + i];
    __syncthreads();

    // per-lane x row, f32 (exact input values)
    float xv[NIN];
#pragma unroll
    for (int i = 0; i < NIN; ++i) xv[i] = sx[lane * NIN + i];

    const int h0 = wq * 25;

    // ---------------- Phase 1: chains -> bit-trains (branch-free) -------
    unsigned int badmask = 0;                  // wave-uniform per-j triggers
    for (int j = 0; j < 25; ++j) {
        const int h = h0 + j;                  // wave-uniform -> s_load weights
        float c32 = 0.f;
#pragma unroll
        for (int i = 0; i < NIN; ++i) c32 = fmaf(W1[h * NIN + i], xv[i], c32);
        c32 += b1[h];
        const float k  = c32 - 0.05f;          // u-chain: u = m-1
        const float k1 = c32 - 1.05f;

        float u = -1.0f, ming = 1e30f;
        bool  s = false;                       // spike(t-1) == reset(t)
        unsigned int mask = 0;                 // bit for step t at pos 24-t
#pragma unroll
        for (int t = 0; t < TSTEPS; ++t) {
            u = fmaf(0.95f, u, s ? k1 : k);    // leaky integrate + fused reset
            s = (u > 0.0f);                    // spike (== m > 1)
            mask = (mask << 1) | (s ? 1u : 0u);
            ming = fminf(ming, fabsf(u));      // margin (abs modifier free)
        }
        sbits[wq][j][lane] = mask;
        badmask |= __any(ming < EPS) ? (1u << j) : 0u;
    }

    // ---------------- rare f64 arbitration (out of hot loop) ------------
    if (badmask) {
        for (int j = 0; j < 25; ++j) {
            if (!((badmask >> j) & 1u)) continue;   // wave-uniform branch
            const int h = h0 + j;
            float c32 = 0.f;                        // identical fmaf order
#pragma unroll
            for (int i = 0; i < NIN; ++i) c32 = fmaf(W1[h * NIN + i], xv[i], c32);
            c32 += b1[h];
            const float k  = c32 - 0.05f;
            const float k1 = c32 - 1.05f;
            double c64 = 0.0;
#pragma unroll
            for (int i = 0; i < NIN; ++i)
                c64 += (double)W1[h * NIN + i] * (double)xv[i];
            c64 += (double)b1[h];
            const double c1 = c64 - 1.0;

            float  ur = -1.0f; bool sr = false;     // f32 replay == main chain
            double md = 0.0;   bool sd = false;     // exact f64 chain
            unsigned int fix = 0;
#pragma unroll
            for (int t = 0; t < TSTEPS; ++t) {
                ur = fmaf(0.95f, ur, sr ? k1 : k);
                sr = (ur > 0.0f);
                md = 0.95 * md + (sd ? c1 : c64);
                sd = (md > 1.0);
                fix = (fix << 1) | ((sr != sd) ? 1u : 0u);
            }
            sbits[wq][j][lane] ^= fix;              // patch to f64 decisions
        }
    }

    // ---------------- Phase 2: bit-trains -> fc2 partials + epilogue ----
    double m20 = 0.0, m21 = 0.0;
    const double bb0 = (double)b2[0], bb1 = (double)b2[1];

#pragma unroll 1
    for (int c = 0; c < TSTEPS / CHUNK; ++c) {
        float acc0[CHUNK], acc1[CHUNK];            // 10 live accumulators
#pragma unroll
        for (int i = 0; i < CHUNK; ++i) { acc0[i] = 0.f; acc1[i] = 0.f; }

#pragma unroll
        for (int j = 0; j < 25; ++j) {
            const unsigned int bits = sbits[wq][j][lane];
            const float w0 = W2[h0 + j], w1 = W2[NHID + h0 + j];
#pragma unroll
            for (int i = 0; i < CHUNK; ++i) {
                // step t = 5c+i lives at bit position 24-t
                const float d = (float)((bits >> (24 - (CHUNK * c + i))) & 1u);
                acc0[i] = fmaf(d, w0, acc0[i]);    // j-ascending per address
                acc1[i] = fmaf(d, w1, acc1[i]);
            }
        }

#pragma unroll
        for (int u = 0; u < CHUNK; ++u)
            sacc[c & 1][wq][u][lane] = (v2f){acc0[u], acc1[u]};
        __syncthreads();
        // wave0 reads buf[c&1] before the NEXT barrier; other waves can't
        // overwrite buf[c&1] until chunk c+2's writes, behind that barrier.
        if (wq == 0) {
#pragma unroll
            for (int u = 0; u < CHUNK; ++u) {
                const int t = c * CHUNK + u;
                v2f q0 = sacc[c & 1][0][u][lane];
                v2f q1 = sacc[c & 1][1][u][lane];
                v2f q2 = sacc[c & 1][2][u][lane];
                v2f q3 = sacc[c & 1][3][u][lane];
                v2f sum = (q0 + q1) + (q2 + q3);   // butterfly bracketing
                double r0 = (m20 > 1.0) ? 1.0 : 0.0;
                double r1 = (m21 > 1.0) ? 1.0 : 0.0;
                m20 = 0.95 * m20 + ((double)sum[0] + bb0) - r0;
                m21 = 0.95 * m21 + ((double)sum[1] + bb1) - r1;
                *(float2*)(out + ((size_t)t * BATCH + b0 + lane) * 2) =
                    make_float2((float)m20, (float)m21);
            }
        }
    }
}

extern "C" void kernel_launch(void* const* d_in, const int* in_sizes, int n_in,
                              void* d_out, int out_size, void* d_ws, size_t ws_size,
                              hipStream_t stream) {
    const float* x  = (const float*)d_in[0];
    const float* W1 = (const float*)d_in[1];
    const float* b1 = (const float*)d_in[2];
    const float* W2 = (const float*)d_in[3];
    const float* b2 = (const float*)d_in[4];
    float* out = (float*)d_out;

    dim3 grid(BATCH / 64), block(256);
    hipLaunchKernelGGL(snn_kernel, grid, block, 0, stream, x, W1, b1, W2, b2, out);
}

// Round 8
// 103.056 us; speedup vs baseline: 1.1821x; 1.0939x over previous
//
#include <hip/hip_runtime.h>

#define BATCH  65536
#define NIN    9
#define NHID   100
#define TSTEPS 25
#define CHUNK  5
#define EPS    3e-5f

typedef float v2f __attribute__((ext_vector_type(2)));

// ROUND-24: R17 hot structure, de-walled. Evidence ledger: R18/R20/R21
// (codegen nudges) = null at 41us; R22 (chain fusion) = scratch spill,
// 65us; R23 (phase split) = +instr, 57us. Remaining mechanism for R17's
// 30% idle @ 4 waves/SIMD: correlated per-j stalls — 12 wave-uniform
// s_loads consumed immediately by the dot, and a divergent fallback
// branch at the bottom of every j that blocks cross-iteration scheduling
// (why unroll pragmas did nothing). This round keeps R17's accumulate
// structure EXACTLY and changes only scheduling freedom:
//  (1) branch-free hot loop: fallback deferred via wave-uniform badmask
//      (R23-proven machinery), patching a0/a1 after the loop. Rare-lane
//      ulp-level patch reordering only; decisions still f64-arbitrated.
//  (2) manual 2-stage scalar pipeline: weight sets A/B live in SGPRs
//      (~12 SGPRs/set, no VGPR cost — the R22 mistake avoided); loads
//      for j+1 issue before body j computes -> SMEM latency hidden
//      under the 25-step chain.
__global__ __launch_bounds__(256, 4) void snn_kernel(
    const float* __restrict__ x,  const float* __restrict__ W1,
    const float* __restrict__ b1, const float* __restrict__ W2,
    const float* __restrict__ b2, float* __restrict__ out)
{
    __shared__ float sx[64 * NIN];              // 2.25 KB staged x rows
    __shared__ v2f   sacc[2][4][CHUNK][64];     // 20.5 KB double-buffered reduce

    const int tid  = threadIdx.x;
    const int lane = tid & 63;
    const int wq   = __builtin_amdgcn_readfirstlane(tid >> 6);
    const int b0   = blockIdx.x * 64;

    for (int i = tid; i < 64 * NIN; i += 256) sx[i] = x[(size_t)b0 * NIN + i];
    __syncthreads();

    // per-lane x row, f32 (exact input values)
    float xv[NIN];
#pragma unroll
    for (int i = 0; i < NIN; ++i) xv[i] = sx[lane * NIN + i];

    // per-step fc2 partial sums (register-resident; AGPR offload tolerated)
    float a0[TSTEPS], a1[TSTEPS];
#pragma unroll
    for (int t = 0; t < TSTEPS; ++t) { a0[t] = 0.f; a1[t] = 0.f; }

    const int h0 = wq * 25;
    unsigned int badmask = 0;                  // wave-uniform fallback triggers

    // branch-free body for unit h0+j, weights passed in (SGPR-resident)
#define SNN_BODY(J, WR, BV, W0, W1V)                                         \
    {                                                                        \
        float c32 = 0.f;                                                     \
        _Pragma("unroll")                                                    \
        for (int i = 0; i < NIN; ++i) c32 = fmaf((WR)[i], xv[i], c32);       \
        c32 += (BV);                                                         \
        const float k  = c32 - 0.05f;                                        \
        const float k1 = c32 - 1.05f;                                        \
        float u = -1.0f, ming = 1e30f;                                       \
        bool  s = false;                                                     \
        _Pragma("unroll")                                                    \
        for (int t = 0; t < TSTEPS; ++t) {                                   \
            u = fmaf(0.95f, u, s ? k1 : k);                                  \
            s = (u > 0.0f);                                                  \
            ming = fminf(ming, fabsf(u));                                    \
            const float d = s ? 1.f : 0.f;                                   \
            a0[t] = fmaf(d, (W0), a0[t]);                                    \
            a1[t] = fmaf(d, (W1V), a1[t]);                                   \
        }                                                                    \
        badmask |= __any(ming < EPS) ? (1u << (J)) : 0u;                     \
    }

    // ---- manual 2-stage scalar pipeline over j (sets A/B in SGPRs) ----
    float WrA[NIN], WrB[NIN];
    float b1A, w0A, w1A, b1B, w0B, w1B;
#pragma unroll
    for (int i = 0; i < NIN; ++i) WrA[i] = W1[h0 * NIN + i];
    b1A = b1[h0]; w0A = W2[h0]; w1A = W2[NHID + h0];

#pragma unroll 1
    for (int jj = 0; jj < 24; jj += 2) {
        const int hB = h0 + jj + 1;            // load set B early (j = jj+1)
#pragma unroll
        for (int i = 0; i < NIN; ++i) WrB[i] = W1[hB * NIN + i];
        b1B = b1[hB]; w0B = W2[hB]; w1B = W2[NHID + hB];

        SNN_BODY(jj, WrA, b1A, w0A, w1A)       // body j = jj (uses set A)

        const int hA = h0 + jj + 2;            // load set A for j = jj+2
#pragma unroll                                  // (jj=22 -> j=24, in range)
        for (int i = 0; i < NIN; ++i) WrA[i] = W1[hA * NIN + i];
        b1A = b1[hA]; w0A = W2[hA]; w1A = W2[NHID + hA];

        SNN_BODY(jj + 1, WrB, b1B, w0B, w1B)   // body j = jj+1 (uses set B)
    }
    SNN_BODY(24, WrA, b1A, w0A, w1A)           // tail j = 24
#undef SNN_BODY

    // ---- rare deferred f64 arbitration (out of hot loop, R23-proven) ----
    if (badmask) {
#pragma unroll 1
        for (int j = 0; j < 25; ++j) {
            if (!((badmask >> j) & 1u)) continue;   // wave-uniform branch
            const int h = h0 + j;
            float c32 = 0.f;                        // identical fmaf order
#pragma unroll
            for (int i = 0; i < NIN; ++i) c32 = fmaf(W1[h * NIN + i], xv[i], c32);
            c32 += b1[h];
            const float k  = c32 - 0.05f;
            const float k1 = c32 - 1.05f;
            const float w0 = W2[h], w1 = W2[NHID + h];
            double c64 = 0.0;
#pragma unroll
            for (int i = 0; i < NIN; ++i)
                c64 += (double)W1[h * NIN + i] * (double)xv[i];
            c64 += (double)b1[h];
            const double c1 = c64 - 1.0;

            float  ur = -1.0f; bool sr = false;     // f32 replay == main chain
            double md = 0.0;   bool sd = false;     // exact f64 chain
#pragma unroll
            for (int t = 0; t < TSTEPS; ++t) {
                ur = fmaf(0.95f, ur, sr ? k1 : k);
                sr = (ur > 0.0f);
                md = 0.95 * md + (sd ? c1 : c64);
                sd = (md > 1.0);
                if (sr != sd) {                     // patch to f64 decision
                    const float sg = sd ? 1.f : -1.f;
                    a0[t] = fmaf(sg, w0, a0[t]);
                    a1[t] = fmaf(sg, w1, a1[t]);
                }
            }
        }
    }

    // chunked cross-wave reduce + mem2 (wave 0), double-buffered LDS.
    // All acc indices compile-time constants (round-9 lesson).
    double m20 = 0.0, m21 = 0.0;
    double bb0 = (double)b2[0], bb1 = (double)b2[1];

#pragma unroll
    for (int k = 0; k < TSTEPS / CHUNK; ++k) {
#pragma unroll
        for (int u = 0; u < CHUNK; ++u)
            sacc[k & 1][wq][u][lane] = (v2f){a0[k * CHUNK + u], a1[k * CHUNK + u]};
        __syncthreads();
        // wave0 reads buf[k&1] before the NEXT barrier; other waves can't
        // overwrite buf[k&1] until chunk k+2's writes, behind that barrier.
        if (wq == 0) {
#pragma unroll
            for (int u = 0; u < CHUNK; ++u) {
                const int t = k * CHUNK + u;
                v2f q0 = sacc[k & 1][0][u][lane];
                v2f q1 = sacc[k & 1][1][u][lane];
                v2f q2 = sacc[k & 1][2][u][lane];
                v2f q3 = sacc[k & 1][3][u][lane];
                v2f sum = (q0 + q1) + (q2 + q3);   // butterfly bracketing
                double r0 = (m20 > 1.0) ? 1.0 : 0.0;
                double r1 = (m21 > 1.0) ? 1.0 : 0.0;
                m20 = 0.95 * m20 + ((double)sum[0] + bb0) - r0;
                m21 = 0.95 * m21 + ((double)sum[1] + bb1) - r1;
                *(float2*)(out + ((size_t)t * BATCH + b0 + lane) * 2) =
                    make_float2((float)m20, (float)m21);
            }
        }
    }
}

extern "C" void kernel_launch(void* const* d_in, const int* in_sizes, int n_in,
                              void* d_out, int out_size, void* d_ws, size_t ws_size,
                              hipStream_t stream) {
    const float* x  = (const float*)d_in[0];
    const float* W1 = (const float*)d_in[1];
    const float* b1 = (const float*)d_in[2];
    const float* W2 = (const float*)d_in[3];
    const float* b2 = (const float*)d_in[4];
    float* out = (float*)d_out;

    dim3 grid(BATCH / 64), block(256);
    hipLaunchKernelGGL(snn_kernel, grid, block, 0, stream, x, W1, b1, W2, b2, out);
}